// Round 1
// baseline (344.362 us; speedup 1.0000x reference)
//
#include <hip/hip_runtime.h>
#include <stdint.h>

#define BATCH 16
#define CH    256
#define NSP   4096   // 64*64 spatial
#define NH    4
#define HD    64

typedef __attribute__((ext_vector_type(8))) short bf16x8;
typedef __attribute__((ext_vector_type(4))) float f32x4;
typedef __attribute__((ext_vector_type(4))) unsigned int u32x4;

__device__ __forceinline__ short f2bf(float f) {
    union { float f; unsigned u; } v; v.f = f;
    unsigned r = (v.u + 0x7fffu + ((v.u >> 16) & 1u)) >> 16;
    return (short)r;
}
__device__ __forceinline__ float bf2f(short s) {
    union { float f; unsigned u; } v; v.u = ((unsigned)(unsigned short)s) << 16;
    return v.f;
}

// ---------------- weight fp32 -> bf16 ----------------
__global__ __launch_bounds__(256) void k_convert_w(
        const float* __restrict__ wq, const float* __restrict__ wo,
        short* __restrict__ wq_bf, short* __restrict__ wo_bf) {
    int i = blockIdx.x * 256 + threadIdx.x;
    if (i < 768 * 256) wq_bf[i] = f2bf(wq[i]);
    if (i < 256 * 256) wo_bf[i] = f2bf(wo[i]);
}

// ---------------- GroupNorm stats: one block per (b,g), 8ch*4096 contiguous ----------------
__global__ __launch_bounds__(256) void k_gn_stats(
        const float* __restrict__ x, float* __restrict__ mu, float* __restrict__ rstd) {
    int bg = blockIdx.x; // 0..511
    const float4* p = (const float4*)(x + (size_t)bg * 32768);
    float s = 0.f, sq = 0.f;
    for (int i = threadIdx.x; i < 8192; i += 256) {
        float4 v = p[i];
        s  += v.x + v.y + v.z + v.w;
        sq += v.x * v.x + v.y * v.y + v.z * v.z + v.w * v.w;
    }
    for (int off = 32; off; off >>= 1) { s += __shfl_down(s, off); sq += __shfl_down(sq, off); }
    __shared__ float ls[4], lq[4];
    int w = threadIdx.x >> 6;
    if ((threadIdx.x & 63) == 0) { ls[w] = s; lq[w] = sq; }
    __syncthreads();
    if (threadIdx.x == 0) {
        float S = ls[0] + ls[1] + ls[2] + ls[3];
        float Q = lq[0] + lq[1] + lq[2] + lq[3];
        float m = S / 32768.f;
        float var = Q / 32768.f - m * m;
        mu[bg] = m; rstd[bg] = rsqrtf(var + 1e-5f);
    }
}

// ---------------- GN apply + transpose: write xn_t[b][n][c] bf16 ----------------
__global__ __launch_bounds__(256) void k_gn_apply(
        const float* __restrict__ x, const float* __restrict__ gamma,
        const float* __restrict__ beta, const float* __restrict__ mu,
        const float* __restrict__ rstd, short* __restrict__ xn_t) {
    int b = blockIdx.y;
    int n0 = blockIdx.x * 64;
    __shared__ short lds[64 * 264];
    __shared__ float smu[32], srstd[32], sg[256], sb[256];
    int t = threadIdx.x;
    if (t < 32) { smu[t] = mu[b * 32 + t]; srstd[t] = rstd[b * 32 + t]; }
    sg[t] = gamma[t]; sb[t] = beta[t];
    __syncthreads();
    int nl4 = (t & 15) * 4, cq = t >> 4; // 16 channels per iter, float4 per thread
    const float* xb = x + (size_t)b * CH * NSP;
    for (int cb = 0; cb < 16; cb++) {
        int c = cb * 16 + cq;
        int g = c >> 3;
        float4 v = *(const float4*)(xb + (size_t)c * NSP + n0 + nl4);
        float sc = srstd[g] * sg[c];
        float sh = sb[c] - smu[g] * sc;
        lds[(nl4 + 0) * 264 + c] = f2bf(v.x * sc + sh);
        lds[(nl4 + 1) * 264 + c] = f2bf(v.y * sc + sh);
        lds[(nl4 + 2) * 264 + c] = f2bf(v.z * sc + sh);
        lds[(nl4 + 3) * 264 + c] = f2bf(v.w * sc + sh);
    }
    __syncthreads();
    short* outb = xn_t + ((size_t)b * NSP + n0) * CH;
    #pragma unroll
    for (int i = 0; i < 8; i++) {
        int ch = t + i * 256;          // 2048 chunks of 8
        int row = ch >> 5, cc = (ch & 31) * 8;
        *(u32x4*)(outb + (size_t)row * CH + cc) = *(const u32x4*)(lds + row * 264 + cc);
    }
}

// ---------------- QKV GEMM: C[768,4096] = Wqkv[768,256] @ xn_t[n][c]^T per batch ----------------
// mt 0-1 -> q (elu+1, transpose to q_t[b][h][n][d]); mt 2-3 -> k (elu+1, natural); mt 4-5 -> v
__global__ __launch_bounds__(256) void k_qkv_gemm(
        const short* __restrict__ wq_bf, const float* __restrict__ b_qkv,
        const short* __restrict__ xn_t, short* __restrict__ q_t,
        short* __restrict__ kvnat) {
    int b = blockIdx.z, mt = blockIdx.y, nt = blockIdx.x;
    __shared__ union SM {
        struct { short a[128 * 40]; short bm[128 * 40]; } st;
        short c[128 * 136];
    } sm;
    int t = threadIdx.x, lane = t & 63, wv = t >> 6;
    int lr = lane & 15, quad = lane >> 4;
    int wm = (wv & 1) * 64, wn = (wv >> 1) * 64;
    f32x4 acc[4][4] = {};
    const short* Ab = wq_bf + (size_t)mt * 128 * 256;
    const short* Bb = xn_t + ((size_t)b * NSP + (size_t)nt * 128) * 256;
    for (int k0 = 0; k0 < 256; k0 += 32) {
        #pragma unroll
        for (int i = 0; i < 2; i++) {
            int ch = t + i * 256;
            int row = ch >> 2, kc = (ch & 3) * 8;
            *(u32x4*)(sm.st.a  + row * 40 + kc) = *(const u32x4*)(Ab + (size_t)row * 256 + k0 + kc);
            *(u32x4*)(sm.st.bm + row * 40 + kc) = *(const u32x4*)(Bb + (size_t)row * 256 + k0 + kc);
        }
        __syncthreads();
        bf16x8 afr[4], bfr[4];
        #pragma unroll
        for (int mi = 0; mi < 4; mi++) afr[mi] = *(const bf16x8*)(sm.st.a  + (wm + mi * 16 + lr) * 40 + quad * 8);
        #pragma unroll
        for (int ni = 0; ni < 4; ni++) bfr[ni] = *(const bf16x8*)(sm.st.bm + (wn + ni * 16 + lr) * 40 + quad * 8);
        #pragma unroll
        for (int mi = 0; mi < 4; mi++)
            #pragma unroll
            for (int ni = 0; ni < 4; ni++)
                acc[mi][ni] = __builtin_amdgcn_mfma_f32_16x16x32_bf16(afr[mi], bfr[ni], acc[mi][ni], 0, 0, 0);
        __syncthreads();
    }
    bool is_q = (mt < 2);
    int obase = mt * 128;
    #pragma unroll
    for (int mi = 0; mi < 4; mi++)
      #pragma unroll
      for (int ni = 0; ni < 4; ni++)
        #pragma unroll
        for (int r = 0; r < 4; r++) {
            int ol = wm + mi * 16 + quad * 4 + r;
            int nl = wn + ni * 16 + lr;
            int o = obase + ol;
            float v = acc[mi][ni][r] + b_qkv[o];
            if (o < 512) v = v > 0.f ? v + 1.f : __expf(v);   // elu(x)+1
            if (is_q) sm.c[nl * 136 + ol] = f2bf(v);          // transposed staging [n][o]
            else      sm.c[ol * 136 + nl] = f2bf(v);          // natural staging [o][n]
        }
    __syncthreads();
    if (is_q) {
        short* qb = q_t + (size_t)b * NH * NSP * HD;
        #pragma unroll
        for (int i = 0; i < 8; i++) {
            int ch = t + i * 256;
            int row = ch >> 4, c8 = (ch & 15) * 8;
            int h = mt * 2 + (c8 >> 6), d0 = c8 & 63;
            int n = nt * 128 + row;
            *(u32x4*)(qb + ((size_t)h * NSP + n) * HD + d0) = *(const u32x4*)(sm.c + row * 136 + c8);
        }
    } else {
        short* ob = kvnat + (size_t)b * 512 * NSP + (size_t)(obase - 256) * NSP + (size_t)nt * 128;
        #pragma unroll
        for (int i = 0; i < 8; i++) {
            int ch = t + i * 256;
            int row = ch >> 4, nc = (ch & 15) * 8;
            *(u32x4*)(ob + (size_t)row * NSP + nc) = *(const u32x4*)(sm.c + row * 136 + nc);
        }
    }
}

// ---------------- kv^T[e][d] = sum_n v[e,n]*k[d,n] and ksum[d], K-split with atomics ----------------
__global__ __launch_bounds__(256) void k_kv(
        const short* __restrict__ kvnat, float* __restrict__ kvT_g, float* __restrict__ ksum_g) {
    int bh = blockIdx.x, ks = blockIdx.y;
    int b = bh >> 2, h = bh & 3;
    __shared__ short kl[64 * 136];
    __shared__ short vl[64 * 136];
    __shared__ float kvred[64 * 65];
    __shared__ float ksred[64];
    int t = threadIdx.x, lane = t & 63, wv = t >> 6, lr = lane & 15, quad = lane >> 4;
    const short* kbase = kvnat + (size_t)b * 512 * NSP + (size_t)(h * 64) * NSP + (size_t)ks * 512;
    const short* vbase = kbase + (size_t)256 * NSP;
    f32x4 acc[4][4] = {};
    float ksacc = 0.f;
    int kd = t >> 2, q4 = t & 3;
    for (int cb = 0; cb < 4; cb++) {
        int nb = cb * 128;
        #pragma unroll
        for (int i = 0; i < 4; i++) {
            int ch = t + i * 256;
            int row = ch >> 4, nc = (ch & 15) * 8;
            *(u32x4*)(kl + row * 136 + nc) = *(const u32x4*)(kbase + (size_t)row * NSP + nb + nc);
            *(u32x4*)(vl + row * 136 + nc) = *(const u32x4*)(vbase + (size_t)row * NSP + nb + nc);
        }
        __syncthreads();
        int kk = wv * 32; // waves partition K within the 128-chunk
        bf16x8 afr[4], bfr[4];
        #pragma unroll
        for (int mi = 0; mi < 4; mi++) afr[mi] = *(const bf16x8*)(vl + (mi * 16 + lr) * 136 + kk + quad * 8);
        #pragma unroll
        for (int ni = 0; ni < 4; ni++) bfr[ni] = *(const bf16x8*)(kl + (ni * 16 + lr) * 136 + kk + quad * 8);
        #pragma unroll
        for (int mi = 0; mi < 4; mi++)
            #pragma unroll
            for (int ni = 0; ni < 4; ni++)
                acc[mi][ni] = __builtin_amdgcn_mfma_f32_16x16x32_bf16(afr[mi], bfr[ni], acc[mi][ni], 0, 0, 0);
        #pragma unroll
        for (int j = 0; j < 32; j++) ksacc += bf2f(kl[kd * 136 + q4 * 32 + j]);
        __syncthreads();
    }
    for (int i = t; i < 64 * 65; i += 256) kvred[i] = 0.f;
    if (t < 64) ksred[t] = 0.f;
    __syncthreads();
    #pragma unroll
    for (int mi = 0; mi < 4; mi++)
      #pragma unroll
      for (int ni = 0; ni < 4; ni++)
        #pragma unroll
        for (int r = 0; r < 4; r++) {
            int e = mi * 16 + quad * 4 + r, d = ni * 16 + lr;
            atomicAdd(&kvred[e * 65 + d], acc[mi][ni][r]);
        }
    atomicAdd(&ksred[kd], ksacc);
    __syncthreads();
    float* kvg = kvT_g + (size_t)bh * 4096;
    for (int i = t; i < 4096; i += 256)
        atomicAdd(&kvg[i], kvred[(i >> 6) * 65 + (i & 63)]);
    if (t < 64) atomicAdd(&ksum_g[bh * 64 + t], ksred[t]);
}

// ---------------- attn: outT[n][e] = q_t[n,:]·kv[:,e] / denom[n]; write attn_t[b][n][h*64+e] ----------------
__global__ __launch_bounds__(256) void k_attn(
        const short* __restrict__ q_t, const float* __restrict__ kvT_g,
        const float* __restrict__ ksum_g, short* __restrict__ attn_t) {
    int nt = blockIdx.x, h = blockIdx.y, b = blockIdx.z;
    int bh = b * 4 + h;
    __shared__ short ql[128 * 72];
    __shared__ short kvl[64 * 72];
    __shared__ float ksl[64];
    __shared__ float dnl[128];
    int t = threadIdx.x, lane = t & 63, wv = t >> 6, lr = lane & 15, quad = lane >> 4;
    const short* qb = q_t + ((size_t)bh * NSP + (size_t)nt * 128) * HD;
    #pragma unroll
    for (int i = 0; i < 4; i++) {
        int ch = t + i * 256;
        int row = ch >> 3, dc = (ch & 7) * 8;
        *(u32x4*)(ql + row * 72 + dc) = *(const u32x4*)(qb + (size_t)row * HD + dc);
    }
    const float* kvg = kvT_g + (size_t)bh * 4096;
    for (int i = t; i < 4096; i += 256)
        kvl[(i >> 6) * 72 + (i & 63)] = f2bf(kvg[i]);
    if (t < 64) ksl[t] = ksum_g[bh * 64 + t];
    __syncthreads();
    if (t < 128) {
        float s = 0.f;
        #pragma unroll
        for (int d = 0; d < 64; d++) s += bf2f(ql[t * 72 + d]) * ksl[d];
        dnl[t] = 1.f / (s + 1e-6f);
    }
    __syncthreads();
    f32x4 acc[2][4] = {};
    int mbase = wv * 32;
    #pragma unroll
    for (int kk = 0; kk < 64; kk += 32) {
        bf16x8 afr[2], bfr[4];
        #pragma unroll
        for (int mi = 0; mi < 2; mi++) afr[mi] = *(const bf16x8*)(ql + (mbase + mi * 16 + lr) * 72 + kk + quad * 8);
        #pragma unroll
        for (int ni = 0; ni < 4; ni++) bfr[ni] = *(const bf16x8*)(kvl + (ni * 16 + lr) * 72 + kk + quad * 8);
        #pragma unroll
        for (int mi = 0; mi < 2; mi++)
            #pragma unroll
            for (int ni = 0; ni < 4; ni++)
                acc[mi][ni] = __builtin_amdgcn_mfma_f32_16x16x32_bf16(afr[mi], bfr[ni], acc[mi][ni], 0, 0, 0);
    }
    short* ob = attn_t + ((size_t)b * NSP + (size_t)nt * 128) * CH + h * 64;
    #pragma unroll
    for (int mi = 0; mi < 2; mi++)
      #pragma unroll
      for (int ni = 0; ni < 4; ni++)
        #pragma unroll
        for (int r = 0; r < 4; r++) {
            int nl = mbase + mi * 16 + quad * 4 + r;
            int e = ni * 16 + lr;
            ob[(size_t)nl * CH + e] = f2bf(acc[mi][ni][r] * dnl[nl]);
        }
}

// ---------------- final: out[b,o,n] = Wout[o,:]·attn_t[n,:] + b_out[o] + x[b,o,n] ----------------
__global__ __launch_bounds__(256) void k_out_gemm(
        const short* __restrict__ wo_bf, const float* __restrict__ b_out,
        const short* __restrict__ attn_t, const float* __restrict__ x,
        float* __restrict__ out) {
    int b = blockIdx.z, mt = blockIdx.y, nt = blockIdx.x;
    __shared__ short lds_a[128 * 40];
    __shared__ short lds_b[128 * 40];
    int t = threadIdx.x, lane = t & 63, wv = t >> 6, lr = lane & 15, quad = lane >> 4;
    int wm = (wv & 1) * 64, wn = (wv >> 1) * 64;
    f32x4 acc[4][4] = {};
    const short* Ab = wo_bf + (size_t)mt * 128 * 256;
    const short* Bb = attn_t + ((size_t)b * NSP + (size_t)nt * 128) * 256;
    for (int k0 = 0; k0 < 256; k0 += 32) {
        #pragma unroll
        for (int i = 0; i < 2; i++) {
            int ch = t + i * 256;
            int row = ch >> 2, kc = (ch & 3) * 8;
            *(u32x4*)(lds_a + row * 40 + kc) = *(const u32x4*)(Ab + (size_t)row * 256 + k0 + kc);
            *(u32x4*)(lds_b + row * 40 + kc) = *(const u32x4*)(Bb + (size_t)row * 256 + k0 + kc);
        }
        __syncthreads();
        bf16x8 afr[4], bfr[4];
        #pragma unroll
        for (int mi = 0; mi < 4; mi++) afr[mi] = *(const bf16x8*)(lds_a + (wm + mi * 16 + lr) * 40 + quad * 8);
        #pragma unroll
        for (int ni = 0; ni < 4; ni++) bfr[ni] = *(const bf16x8*)(lds_b + (wn + ni * 16 + lr) * 40 + quad * 8);
        #pragma unroll
        for (int mi = 0; mi < 4; mi++)
            #pragma unroll
            for (int ni = 0; ni < 4; ni++)
                acc[mi][ni] = __builtin_amdgcn_mfma_f32_16x16x32_bf16(afr[mi], bfr[ni], acc[mi][ni], 0, 0, 0);
        __syncthreads();
    }
    const float* xb = x + ((size_t)b * CH + (size_t)mt * 128) * NSP + (size_t)nt * 128;
    float* outb = out + ((size_t)b * CH + (size_t)mt * 128) * NSP + (size_t)nt * 128;
    #pragma unroll
    for (int mi = 0; mi < 4; mi++)
      #pragma unroll
      for (int ni = 0; ni < 4; ni++)
        #pragma unroll
        for (int r = 0; r < 4; r++) {
            int ol = wm + mi * 16 + quad * 4 + r;
            int nl = wn + ni * 16 + lr;
            int o = mt * 128 + ol;
            outb[(size_t)ol * NSP + nl] = acc[mi][ni][r] + b_out[o] + xb[(size_t)ol * NSP + nl];
        }
}

extern "C" void kernel_launch(void* const* d_in, const int* in_sizes, int n_in,
                              void* d_out, int out_size, void* d_ws, size_t ws_size,
                              hipStream_t stream) {
    const float* x     = (const float*)d_in[0];
    const float* gamma = (const float*)d_in[1];
    const float* beta  = (const float*)d_in[2];
    const float* w_qkv = (const float*)d_in[3];
    const float* b_qkv = (const float*)d_in[4];
    const float* w_out = (const float*)d_in[5];
    const float* b_out = (const float*)d_in[6];
    float* out = (float*)d_out;

    // workspace layout (~130 MiB)
    char* ws = (char*)d_ws;
    size_t off = 0;
    float* mu    = (float*)(ws + off); off += 2048;
    float* rstd  = (float*)(ws + off); off += 2048;
    short* wq_bf = (short*)(ws + off); off += (size_t)768 * 256 * 2;
    short* wo_bf = (short*)(ws + off); off += (size_t)256 * 256 * 2;
    short* xn_t  = (short*)(ws + off);                    // [b][n][c] bf16
    short* attn_t = xn_t;                                 // aliased: xn_t dead after QKV GEMM
    off += (size_t)BATCH * NSP * CH * 2;
    short* q_t   = (short*)(ws + off); off += (size_t)BATCH * NSP * CH * 2;  // [b][h][n][d]
    short* kvnat = (short*)(ws + off); off += (size_t)BATCH * 512 * NSP * 2; // [b][k:256|v:256][n]
    float* kvT_g = (float*)(ws + off); off += (size_t)64 * 4096 * 4;         // [bh][e][d]
    float* ksum_g = (float*)(ws + off); off += (size_t)64 * 64 * 4;          // [bh][d]

    if (ws_size < off) return;  // workspace too small — will fail validation visibly

    k_convert_w<<<768, 256, 0, stream>>>(w_qkv, w_out, wq_bf, wo_bf);
    k_gn_stats<<<512, 256, 0, stream>>>(x, mu, rstd);
    k_gn_apply<<<dim3(64, 16), 256, 0, stream>>>(x, gamma, beta, mu, rstd, xn_t);
    k_qkv_gemm<<<dim3(32, 6, 16), 256, 0, stream>>>(wq_bf, b_qkv, xn_t, q_t, kvnat);
    hipMemsetAsync(kvT_g, 0, (size_t)(64 * 4096 + 64 * 64) * 4, stream);
    k_kv<<<dim3(64, 8), 256, 0, stream>>>(kvnat, kvT_g, ksum_g);
    k_attn<<<dim3(32, 4, 16), 256, 0, stream>>>(q_t, kvT_g, ksum_g, attn_t);
    k_out_gemm<<<dim3(32, 2, 16), 256, 0, stream>>>(wo_bf, b_out, attn_t, x, out);
}

// Round 2
// 311.142 us; speedup vs baseline: 1.1068x; 1.1068x over previous
//
#include <hip/hip_runtime.h>
#include <stdint.h>

#define BATCH 16
#define CH    256
#define NSP   4096   // 64*64 spatial
#define NH    4
#define HD    64

typedef __attribute__((ext_vector_type(8))) short bf16x8;
typedef __attribute__((ext_vector_type(4))) float f32x4;
typedef __attribute__((ext_vector_type(4))) unsigned int u32x4;

__device__ __forceinline__ short f2bf(float f) {
    union { float f; unsigned u; } v; v.f = f;
    unsigned r = (v.u + 0x7fffu + ((v.u >> 16) & 1u)) >> 16;
    return (short)r;
}
__device__ __forceinline__ float bf2f(short s) {
    union { float f; unsigned u; } v; v.u = ((unsigned)(unsigned short)s) << 16;
    return v.f;
}

// ---------------- weight fp32 -> bf16 ----------------
__global__ __launch_bounds__(256) void k_convert_w(
        const float* __restrict__ wq, const float* __restrict__ wo,
        short* __restrict__ wq_bf, short* __restrict__ wo_bf) {
    int i = blockIdx.x * 256 + threadIdx.x;
    if (i < 768 * 256) wq_bf[i] = f2bf(wq[i]);
    if (i < 256 * 256) wo_bf[i] = f2bf(wo[i]);
}

// ---------------- GroupNorm stats: one block per (b,g), 8ch*4096 contiguous ----------------
__global__ __launch_bounds__(256) void k_gn_stats(
        const float* __restrict__ x, float* __restrict__ mu, float* __restrict__ rstd) {
    int bg = blockIdx.x; // 0..511
    const float4* p = (const float4*)(x + (size_t)bg * 32768);
    float s = 0.f, sq = 0.f;
    for (int i = threadIdx.x; i < 8192; i += 256) {
        float4 v = p[i];
        s  += v.x + v.y + v.z + v.w;
        sq += v.x * v.x + v.y * v.y + v.z * v.z + v.w * v.w;
    }
    for (int off = 32; off; off >>= 1) { s += __shfl_down(s, off); sq += __shfl_down(sq, off); }
    __shared__ float ls[4], lq[4];
    int w = threadIdx.x >> 6;
    if ((threadIdx.x & 63) == 0) { ls[w] = s; lq[w] = sq; }
    __syncthreads();
    if (threadIdx.x == 0) {
        float S = ls[0] + ls[1] + ls[2] + ls[3];
        float Q = lq[0] + lq[1] + lq[2] + lq[3];
        float m = S / 32768.f;
        float var = Q / 32768.f - m * m;
        mu[bg] = m; rstd[bg] = rsqrtf(var + 1e-5f);
    }
}

// ---------------- GN apply + transpose: write xn_t[b][n][c] bf16 ----------------
__global__ __launch_bounds__(256) void k_gn_apply(
        const float* __restrict__ x, const float* __restrict__ gamma,
        const float* __restrict__ beta, const float* __restrict__ mu,
        const float* __restrict__ rstd, short* __restrict__ xn_t) {
    int b = blockIdx.y;
    int n0 = blockIdx.x * 64;
    __shared__ short lds[64 * 264];
    __shared__ float smu[32], srstd[32], sg[256], sb[256];
    int t = threadIdx.x;
    if (t < 32) { smu[t] = mu[b * 32 + t]; srstd[t] = rstd[b * 32 + t]; }
    sg[t] = gamma[t]; sb[t] = beta[t];
    __syncthreads();
    int nl4 = (t & 15) * 4, cq = t >> 4; // 16 channels per iter, float4 per thread
    const float* xb = x + (size_t)b * CH * NSP;
    for (int cb = 0; cb < 16; cb++) {
        int c = cb * 16 + cq;
        int g = c >> 3;
        float4 v = *(const float4*)(xb + (size_t)c * NSP + n0 + nl4);
        float sc = srstd[g] * sg[c];
        float sh = sb[c] - smu[g] * sc;
        lds[(nl4 + 0) * 264 + c] = f2bf(v.x * sc + sh);
        lds[(nl4 + 1) * 264 + c] = f2bf(v.y * sc + sh);
        lds[(nl4 + 2) * 264 + c] = f2bf(v.z * sc + sh);
        lds[(nl4 + 3) * 264 + c] = f2bf(v.w * sc + sh);
    }
    __syncthreads();
    short* outb = xn_t + ((size_t)b * NSP + n0) * CH;
    #pragma unroll
    for (int i = 0; i < 8; i++) {
        int ch = t + i * 256;          // 2048 chunks of 8
        int row = ch >> 5, cc = (ch & 31) * 8;
        *(u32x4*)(outb + (size_t)row * CH + cc) = *(const u32x4*)(lds + row * 264 + cc);
    }
}

// ---------------- QKV GEMM + fused kv^T ----------------
// mt 0-1: q rows (elu+1) -> q_t[b][h][n][d]
// mt 2-5: head h=mt-2: rows 0..63 = k_h (elu+1), rows 64..127 = v_h.
//         second MFMA pass: kvT[e][d] += v·k^T over this n-tile (global atomics),
//         ksum[d] += sum_n k (global atomics).
__global__ __launch_bounds__(256) void k_qkv_gemm(
        const short* __restrict__ wq_bf, const float* __restrict__ b_qkv,
        const short* __restrict__ xn_t, short* __restrict__ q_t,
        float* __restrict__ kvT_g, float* __restrict__ ksum_g) {
    int b = blockIdx.z, mt = blockIdx.y, nt = blockIdx.x;
    bool is_q = (mt < 2);
    int h = mt - 2;
    __shared__ union SM {
        struct { short a[128 * 40]; short bm[128 * 40]; } st;
        short c[128 * 136];
    } sm;
    __shared__ float ksred[64];
    int t = threadIdx.x, lane = t & 63, wv = t >> 6;
    int lr = lane & 15, quad = lane >> 4;
    int wm = (wv & 1) * 64, wn = (wv >> 1) * 64;
    f32x4 acc[4][4] = {};
    const short* Bb = xn_t + ((size_t)b * NSP + (size_t)nt * 128) * 256;
    for (int k0 = 0; k0 < 256; k0 += 32) {
        #pragma unroll
        for (int i = 0; i < 2; i++) {
            int ch = t + i * 256;
            int row = ch >> 2, kc = (ch & 3) * 8;
            int grow = is_q ? (mt * 128 + row)
                            : (row < 64 ? 256 + h * 64 + row : 512 + h * 64 + (row - 64));
            *(u32x4*)(sm.st.a  + row * 40 + kc) = *(const u32x4*)(wq_bf + (size_t)grow * 256 + k0 + kc);
            *(u32x4*)(sm.st.bm + row * 40 + kc) = *(const u32x4*)(Bb + (size_t)row * 256 + k0 + kc);
        }
        __syncthreads();
        bf16x8 afr[4], bfr[4];
        #pragma unroll
        for (int mi = 0; mi < 4; mi++) afr[mi] = *(const bf16x8*)(sm.st.a  + (wm + mi * 16 + lr) * 40 + quad * 8);
        #pragma unroll
        for (int ni = 0; ni < 4; ni++) bfr[ni] = *(const bf16x8*)(sm.st.bm + (wn + ni * 16 + lr) * 40 + quad * 8);
        #pragma unroll
        for (int mi = 0; mi < 4; mi++)
            #pragma unroll
            for (int ni = 0; ni < 4; ni++)
                acc[mi][ni] = __builtin_amdgcn_mfma_f32_16x16x32_bf16(afr[mi], bfr[ni], acc[mi][ni], 0, 0, 0);
        __syncthreads();
    }
    if (t < 64) ksred[t] = 0.f;
    #pragma unroll
    for (int mi = 0; mi < 4; mi++)
      #pragma unroll
      for (int ni = 0; ni < 4; ni++)
        #pragma unroll
        for (int r = 0; r < 4; r++) {
            int ol = wm + mi * 16 + quad * 4 + r;
            int nl = wn + ni * 16 + lr;
            int o = is_q ? (mt * 128 + ol)
                         : (ol < 64 ? 256 + h * 64 + ol : 512 + h * 64 + (ol - 64));
            float v = acc[mi][ni][r] + b_qkv[o];
            if (o < 512) v = v > 0.f ? v + 1.f : __expf(v);   // elu(x)+1
            if (is_q) sm.c[nl * 136 + ol] = f2bf(v);          // transposed staging [n][o]
            else      sm.c[ol * 136 + nl] = f2bf(v);          // natural staging [o][n]
        }
    __syncthreads();
    if (is_q) {
        short* qb = q_t + (size_t)b * NH * NSP * HD;
        #pragma unroll
        for (int i = 0; i < 8; i++) {
            int ch = t + i * 256;
            int row = ch >> 4, c8 = (ch & 15) * 8;
            int hh = mt * 2 + (c8 >> 6), d0 = c8 & 63;
            int n = nt * 128 + row;
            *(u32x4*)(qb + ((size_t)hh * NSP + n) * HD + d0) = *(const u32x4*)(sm.c + row * 136 + c8);
        }
    } else {
        // ksum partials: thread t sums k[d=t>>2][n-chunk (t&3)*32..+32]
        {
            int kd = t >> 2, nc0 = (t & 3) * 32;
            float s = 0.f;
            #pragma unroll
            for (int j = 0; j < 32; j++) s += bf2f(sm.c[kd * 136 + nc0 + j]);
            atomicAdd(&ksred[kd], s);
        }
        // kv^T pass: A = v rows (64..127) [e][n], B = k rows (0..63) [d][n], K=128.
        // Wave wv owns e-rows wv*16..wv*16+15 exclusively -> no cross-wave reduce.
        f32x4 acc2[4] = {};
        #pragma unroll
        for (int kk = 0; kk < 128; kk += 32) {
            bf16x8 af = *(const bf16x8*)(sm.c + (64 + wv * 16 + lr) * 136 + kk + quad * 8);
            bf16x8 bf[4];
            #pragma unroll
            for (int ni = 0; ni < 4; ni++)
                bf[ni] = *(const bf16x8*)(sm.c + (ni * 16 + lr) * 136 + kk + quad * 8);
            #pragma unroll
            for (int ni = 0; ni < 4; ni++)
                acc2[ni] = __builtin_amdgcn_mfma_f32_16x16x32_bf16(af, bf[ni], acc2[ni], 0, 0, 0);
        }
        __syncthreads();   // ksred complete
        int bh = b * NH + h;
        float* kvg = kvT_g + (size_t)bh * 4096;
        #pragma unroll
        for (int ni = 0; ni < 4; ni++)
            #pragma unroll
            for (int r = 0; r < 4; r++) {
                int e = wv * 16 + quad * 4 + r;
                int d = ni * 16 + lr;
                atomicAdd(&kvg[e * 64 + d], acc2[ni][r]);
            }
        if (t < 64) atomicAdd(&ksum_g[bh * 64 + t], ksred[t]);
    }
}

// ---------------- attn: outT[n][e] = q_t[n,:]·kv[:,e] / denom[n]; write attn_t[b][n][h*64+e] ----------------
__global__ __launch_bounds__(256) void k_attn(
        const short* __restrict__ q_t, const float* __restrict__ kvT_g,
        const float* __restrict__ ksum_g, short* __restrict__ attn_t) {
    int nt = blockIdx.x, h = blockIdx.y, b = blockIdx.z;
    int bh = b * 4 + h;
    __shared__ short ql[128 * 72];
    __shared__ short kvl[64 * 72];
    __shared__ float ksl[64];
    __shared__ float dnl[128];
    int t = threadIdx.x, lane = t & 63, wv = t >> 6, lr = lane & 15, quad = lane >> 4;
    const short* qb = q_t + ((size_t)bh * NSP + (size_t)nt * 128) * HD;
    #pragma unroll
    for (int i = 0; i < 4; i++) {
        int ch = t + i * 256;
        int row = ch >> 3, dc = (ch & 7) * 8;
        *(u32x4*)(ql + row * 72 + dc) = *(const u32x4*)(qb + (size_t)row * HD + dc);
    }
    const float* kvg = kvT_g + (size_t)bh * 4096;
    for (int i = t; i < 4096; i += 256)
        kvl[(i >> 6) * 72 + (i & 63)] = f2bf(kvg[i]);
    if (t < 64) ksl[t] = ksum_g[bh * 64 + t];
    __syncthreads();
    if (t < 128) {
        float s = 0.f;
        #pragma unroll
        for (int d = 0; d < 64; d++) s += bf2f(ql[t * 72 + d]) * ksl[d];
        dnl[t] = 1.f / (s + 1e-6f);
    }
    __syncthreads();
    f32x4 acc[2][4] = {};
    int mbase = wv * 32;
    #pragma unroll
    for (int kk = 0; kk < 64; kk += 32) {
        bf16x8 afr[2], bfr[4];
        #pragma unroll
        for (int mi = 0; mi < 2; mi++) afr[mi] = *(const bf16x8*)(ql + (mbase + mi * 16 + lr) * 72 + kk + quad * 8);
        #pragma unroll
        for (int ni = 0; ni < 4; ni++) bfr[ni] = *(const bf16x8*)(kvl + (ni * 16 + lr) * 72 + kk + quad * 8);
        #pragma unroll
        for (int mi = 0; mi < 2; mi++)
            #pragma unroll
            for (int ni = 0; ni < 4; ni++)
                acc[mi][ni] = __builtin_amdgcn_mfma_f32_16x16x32_bf16(afr[mi], bfr[ni], acc[mi][ni], 0, 0, 0);
    }
    short* ob = attn_t + ((size_t)b * NSP + (size_t)nt * 128) * CH + h * 64;
    #pragma unroll
    for (int mi = 0; mi < 2; mi++)
      #pragma unroll
      for (int ni = 0; ni < 4; ni++)
        #pragma unroll
        for (int r = 0; r < 4; r++) {
            int nl = mbase + mi * 16 + quad * 4 + r;
            int e = ni * 16 + lr;
            ob[(size_t)nl * CH + e] = f2bf(acc[mi][ni][r] * dnl[nl]);
        }
}

// ---------------- final: out[b,o,n] = Wout[o,:]·attn_t[n,:] + b_out[o] + x[b,o,n] ----------------
__global__ __launch_bounds__(256) void k_out_gemm(
        const short* __restrict__ wo_bf, const float* __restrict__ b_out,
        const short* __restrict__ attn_t, const float* __restrict__ x,
        float* __restrict__ out) {
    int b = blockIdx.z, mt = blockIdx.y, nt = blockIdx.x;
    __shared__ short lds_a[128 * 40];
    __shared__ short lds_b[128 * 40];
    int t = threadIdx.x, lane = t & 63, wv = t >> 6, lr = lane & 15, quad = lane >> 4;
    int wm = (wv & 1) * 64, wn = (wv >> 1) * 64;
    f32x4 acc[4][4] = {};
    const short* Ab = wo_bf + (size_t)mt * 128 * 256;
    const short* Bb = attn_t + ((size_t)b * NSP + (size_t)nt * 128) * 256;
    for (int k0 = 0; k0 < 256; k0 += 32) {
        #pragma unroll
        for (int i = 0; i < 2; i++) {
            int ch = t + i * 256;
            int row = ch >> 2, kc = (ch & 3) * 8;
            *(u32x4*)(lds_a + row * 40 + kc) = *(const u32x4*)(Ab + (size_t)row * 256 + k0 + kc);
            *(u32x4*)(lds_b + row * 40 + kc) = *(const u32x4*)(Bb + (size_t)row * 256 + k0 + kc);
        }
        __syncthreads();
        bf16x8 afr[4], bfr[4];
        #pragma unroll
        for (int mi = 0; mi < 4; mi++) afr[mi] = *(const bf16x8*)(lds_a + (wm + mi * 16 + lr) * 40 + quad * 8);
        #pragma unroll
        for (int ni = 0; ni < 4; ni++) bfr[ni] = *(const bf16x8*)(lds_b + (wn + ni * 16 + lr) * 40 + quad * 8);
        #pragma unroll
        for (int mi = 0; mi < 4; mi++)
            #pragma unroll
            for (int ni = 0; ni < 4; ni++)
                acc[mi][ni] = __builtin_amdgcn_mfma_f32_16x16x32_bf16(afr[mi], bfr[ni], acc[mi][ni], 0, 0, 0);
        __syncthreads();
    }
    const float* xb = x + ((size_t)b * CH + (size_t)mt * 128) * NSP + (size_t)nt * 128;
    float* outb = out + ((size_t)b * CH + (size_t)mt * 128) * NSP + (size_t)nt * 128;
    #pragma unroll
    for (int mi = 0; mi < 4; mi++)
      #pragma unroll
      for (int ni = 0; ni < 4; ni++)
        #pragma unroll
        for (int r = 0; r < 4; r++) {
            int ol = wm + mi * 16 + quad * 4 + r;
            int nl = wn + ni * 16 + lr;
            int o = mt * 128 + ol;
            outb[(size_t)ol * NSP + nl] = acc[mi][ni][r] + b_out[o] + xb[(size_t)ol * NSP + nl];
        }
}

extern "C" void kernel_launch(void* const* d_in, const int* in_sizes, int n_in,
                              void* d_out, int out_size, void* d_ws, size_t ws_size,
                              hipStream_t stream) {
    const float* x     = (const float*)d_in[0];
    const float* gamma = (const float*)d_in[1];
    const float* beta  = (const float*)d_in[2];
    const float* w_qkv = (const float*)d_in[3];
    const float* b_qkv = (const float*)d_in[4];
    const float* w_out = (const float*)d_in[5];
    const float* b_out = (const float*)d_in[6];
    float* out = (float*)d_out;

    char* ws = (char*)d_ws;
    size_t off = 0;
    float* mu    = (float*)(ws + off); off += 2048;
    float* rstd  = (float*)(ws + off); off += 2048;
    short* wq_bf = (short*)(ws + off); off += (size_t)768 * 256 * 2;
    short* wo_bf = (short*)(ws + off); off += (size_t)256 * 256 * 2;
    short* xn_t  = (short*)(ws + off);                    // [b][n][c] bf16
    short* attn_t = xn_t;                                 // aliased: xn_t dead after QKV GEMM
    off += (size_t)BATCH * NSP * CH * 2;
    short* q_t   = (short*)(ws + off); off += (size_t)BATCH * NSP * CH * 2;  // [b][h][n][d]
    float* kvT_g = (float*)(ws + off); off += (size_t)64 * 4096 * 4;         // [bh][e][d]
    float* ksum_g = (float*)(ws + off); off += (size_t)64 * 64 * 4;          // [bh][d]

    if (ws_size < off) return;

    k_convert_w<<<768, 256, 0, stream>>>(w_qkv, w_out, wq_bf, wo_bf);
    k_gn_stats<<<512, 256, 0, stream>>>(x, mu, rstd);
    k_gn_apply<<<dim3(64, 16), 256, 0, stream>>>(x, gamma, beta, mu, rstd, xn_t);
    hipMemsetAsync(kvT_g, 0, (size_t)(64 * 4096 + 64 * 64) * 4, stream);
    k_qkv_gemm<<<dim3(32, 6, 16), 256, 0, stream>>>(wq_bf, b_qkv, xn_t, q_t, kvT_g, ksum_g);
    k_attn<<<dim3(32, 4, 16), 256, 0, stream>>>(q_t, kvT_g, ksum_g, attn_t);
    k_out_gemm<<<dim3(32, 2, 16), 256, 0, stream>>>(wo_bf, b_out, attn_t, x, out);
}